// Round 5
// baseline (378.974 us; speedup 1.0000x reference)
//
#include <hip/hip_runtime.h>
#include <hip/hip_bf16.h>
#include <math.h>

#define B_   32
#define CIN  3
#define H_   224
#define W_   224
#define OC   192
#define OH   112
#define OW   112
#define PH   56
#define PW   56
#define NSP  (B_*OH*OW)          // 401408 elements per channel for BN stats
#define PLANE (OH*OW)            // 12544
#define OCG  8                   // oc groups in conv
#define OCPG (OC / OCG)          // 24 ocs per block

static __device__ __forceinline__ unsigned short f2bf(float f) {
    __hip_bfloat16 h = __float2bfloat16(f);   // RNE
    return *reinterpret_cast<unsigned short*>(&h);
}
static __device__ __forceinline__ float bfbits2f(unsigned short u) {
    unsigned int v = ((unsigned int)u) << 16;
    return *reinterpret_cast<float*>(&v);
}

static __device__ __forceinline__ float fexp2(float x) {
#if __has_builtin(__builtin_amdgcn_exp2f)
    return __builtin_amdgcn_exp2f(x);
#else
    return exp2f(x);
#endif
}
static __device__ __forceinline__ float frcp(float x) {
#if __has_builtin(__builtin_amdgcn_rcpf)
    return __builtin_amdgcn_rcpf(x);
#else
    return 1.0f / x;
#endif
}

// tanh-form GELU: x * sigmoid(2*c1*(x + 0.044715 x^3)), via exp2 (+rcp).
// Unimodal: decreasing on (-inf,x0], increasing on [x0,inf), x0 ~ -0.75.
static __device__ __forceinline__ float fast_gelu(float x) {
    float x2 = x * x;
    float inner = fmaf(0.044715f * x2, x, x);
    float e = fexp2(inner * 2.3022082f);      // 2*0.7978845608*log2(e)
    float r = frcp(1.0f + e);
    return x * (e * r);
}

// ---------------- K0: zero the stats accumulators (ws is poisoned 0xAA) ----
__global__ void zero_stats(float* stats) {
    for (int i = threadIdx.x; i < 384; i += 256) stats[i] = 0.f;
}

// ---------------- K1: conv 3x3 s2 p1 + bias, write y bf16 ------------------
// Grid: 392 spatial chunks x 8 oc-groups = 3136 blocks, 256 threads.
// Each thread: 4 consecutive ow, 24 ocs. 81 x-taps in registers; weights
// go through the scalar path (uniform oc). No LDS, no cross-lane ops.
__global__ __launch_bounds__(256) void conv_kernel(
    const float* __restrict__ x, const float* __restrict__ w,
    const float* __restrict__ bias, __hip_bfloat16* __restrict__ y)
{
    int gb = blockIdx.x;
    int og = gb & (OCG - 1);                     // oc group (fastest varying)
    int sp = gb >> 3;                            // spatial chunk 0..391
    int tid = threadIdx.x;

    int spatial = sp * 256 + tid;                // 0..100351
    int owg = spatial % (OW / 4);
    int t   = spatial / (OW / 4);
    int oh  = t % OH;
    int b   = t / OH;
    int ow0 = owg * 4;

    int ih0 = 2 * oh  - 1;
    int iw0 = 2 * ow0 - 1;

    float xv[CIN][3][9];
    #pragma unroll
    for (int c = 0; c < CIN; ++c) {
        #pragma unroll
        for (int r = 0; r < 3; ++r) {
            int ih = ih0 + r;
            bool rv = (ih >= 0) && (ih < H_);
            const float* xrow = x + (((size_t)b * CIN + c) * H_ + (rv ? ih : 0)) * W_;
            #pragma unroll
            for (int j = 0; j < 9; ++j) {
                int iw = iw0 + j;
                bool v = rv && (iw >= 0) && (iw < W_);
                xv[c][r][j] = v ? xrow[iw] : 0.f;
            }
        }
    }

    int oc0 = og * OCPG;
    int ybase = (b * OC + oc0) * PLANE + oh * OW + ow0;

    for (int ocl = 0; ocl < OCPG; ++ocl) {
        float bs = bias[oc0 + ocl];
        float a0 = bs, a1 = bs, a2 = bs, a3 = bs;
        const float* wp = w + (oc0 + ocl) * 27;
        #pragma unroll
        for (int c = 0; c < CIN; ++c)
            #pragma unroll
            for (int r = 0; r < 3; ++r)
                #pragma unroll
                for (int j = 0; j < 3; ++j) {
                    float wv = wp[c * 9 + r * 3 + j];
                    a0 = fmaf(wv, xv[c][r][j + 0], a0);
                    a1 = fmaf(wv, xv[c][r][j + 2], a1);
                    a2 = fmaf(wv, xv[c][r][j + 4], a2);
                    a3 = fmaf(wv, xv[c][r][j + 6], a3);
                }
        ushort4 p;
        p.x = f2bf(a0); p.y = f2bf(a1); p.z = f2bf(a2); p.w = f2bf(a3);
        *reinterpret_cast<ushort4*>(
            reinterpret_cast<unsigned short*>(y) + ybase + ocl * PLANE) = p;
    }
}

// ---------------- K2: per-channel sum / sumsq over y (BW-saturated) -------
__global__ __launch_bounds__(256) void stats_kernel(
    const __hip_bfloat16* __restrict__ y, float* __restrict__ stats)
{
    int plane = blockIdx.x;            // b*OC + oc, 6144 blocks
    int oc = plane % OC;
    const unsigned int* p =
        reinterpret_cast<const unsigned int*>(y) + plane * (PLANE / 2);

    float s = 0.f, s2 = 0.f;
    for (int ch = threadIdx.x; ch < PLANE / 8; ch += 256) {
        uint4 v = reinterpret_cast<const uint4*>(p)[ch];
        unsigned int u[4] = {v.x, v.y, v.z, v.w};
        #pragma unroll
        for (int k = 0; k < 4; ++k) {
            float lo = bfbits2f((unsigned short)(u[k] & 0xffffu));
            float hi = bfbits2f((unsigned short)(u[k] >> 16));
            s  += lo + hi;
            s2 += lo * lo + hi * hi;
        }
    }

    __shared__ float ls[256], ls2[256];
    int tid = threadIdx.x;
    ls[tid] = s; ls2[tid] = s2;
    __syncthreads();
    for (int off = 128; off > 0; off >>= 1) {
        if (tid < off) { ls[tid] += ls[tid + off]; ls2[tid] += ls2[tid + off]; }
        __syncthreads();
    }
    if (tid == 0) {
        atomicAdd(&stats[oc], ls[0]);
        atomicAdd(&stats[OC + oc], ls2[0]);
    }
}

// ---------------- K3: min/max pool + BN affine + 2x GELU ------------------
// max over window of GELU(affine(v)) = max(GELU(affine(vmin)), GELU(affine(vmax)))
// because GELU is unimodal (single minimum). One thread per output, no LDS.
__global__ __launch_bounds__(256) void pool_kernel(
    const __hip_bfloat16* __restrict__ y, const float* __restrict__ stats,
    const float* __restrict__ gamma, const float* __restrict__ beta,
    float* __restrict__ out)
{
    int g = blockIdx.x * 256 + threadIdx.x;     // 19267584 total
    int pw = g % PW;
    int t  = g / PW;
    int ph = t % PH;
    t /= PH;
    int oc = t % OC;
    int b  = t / OC;

    const unsigned short* p =
        reinterpret_cast<const unsigned short*>(y) + (size_t)(b * OC + oc) * PLANE;

    float vmax = -INFINITY, vmin = INFINITY;
    #pragma unroll
    for (int rr = 0; rr < 3; ++rr) {
        int ih = 2 * ph - 1 + rr;
        bool rv = (ih >= 0) && (ih < OH);
        const unsigned short* rowp = p + (rv ? ih : 0) * OW;
        #pragma unroll
        for (int jj = 0; jj < 3; ++jj) {
            int iw = 2 * pw - 1 + jj;
            bool v = rv && (iw >= 0) && (iw < OW);
            if (v) {
                float f = bfbits2f(rowp[iw]);
                vmax = fmaxf(vmax, f);
                vmin = fminf(vmin, f);
            }
        }
    }

    float mean = stats[oc] * (1.0f / (float)NSP);
    float var  = fmaf(-mean, mean, stats[OC + oc] * (1.0f / (float)NSP));
    float inv  = rsqrtf(var + 1e-5f);
    float sc   = gamma[oc] * inv;
    float sh   = fmaf(-mean, sc, beta[oc]);

    // the two affine-mapped extremes (order-agnostic: works for sc<0 too)
    float lo = fmaf(vmin, sc, sh);
    float hi = fmaf(vmax, sc, sh);
    out[g] = fmaxf(fast_gelu(lo), fast_gelu(hi));
}

extern "C" void kernel_launch(void* const* d_in, const int* in_sizes, int n_in,
                              void* d_out, int out_size, void* d_ws, size_t ws_size,
                              hipStream_t stream) {
    const float* x     = (const float*)d_in[0];
    const float* w     = (const float*)d_in[1];
    const float* bias  = (const float*)d_in[2];
    const float* gamma = (const float*)d_in[3];
    const float* beta  = (const float*)d_in[4];
    float* out = (float*)d_out;

    float* stats = (float*)d_ws;                                   // 384 floats of sums
    __hip_bfloat16* y = (__hip_bfloat16*)((char*)d_ws + 4096);     // 154.1 MB bf16

    hipLaunchKernelGGL(zero_stats, dim3(1), dim3(256), 0, stream, stats);
    hipLaunchKernelGGL(conv_kernel, dim3((B_ * OH * (OW / 4)) / 256 * OCG), dim3(256), 0,
                       stream, x, w, bias, y);
    hipLaunchKernelGGL(stats_kernel, dim3(B_ * OC), dim3(256), 0, stream, y, stats);
    hipLaunchKernelGGL(pool_kernel, dim3((B_ * OC * PH * PW) / 256), dim3(256), 0, stream,
                       y, stats, gamma, beta, out);
}

// Round 6
// 268.635 us; speedup vs baseline: 1.4107x; 1.4107x over previous
//
#include <hip/hip_runtime.h>
#include <hip/hip_bf16.h>
#include <math.h>

#define B_   32
#define CIN  3
#define H_   224
#define W_   224
#define OC   192
#define OH   112
#define OW   112
#define PH   56
#define PW   56
#define NSP  (B_*OH*OW)          // 401408 elements per channel for BN stats
#define PLANE (OH*OW)            // 12544

static __device__ __forceinline__ unsigned short f2bf(float f) {
    __hip_bfloat16 h = __float2bfloat16(f);   // RNE
    return *reinterpret_cast<unsigned short*>(&h);
}
static __device__ __forceinline__ float bfbits2f(unsigned short u) {
    unsigned int v = ((unsigned int)u) << 16;
    return *reinterpret_cast<float*>(&v);
}
// bf16 pair unpack from a packed uint (lo = bits[15:0], hi = bits[31:16])
static __device__ __forceinline__ float bf_lo(unsigned int u) {
    unsigned int v = u << 16;
    return *reinterpret_cast<float*>(&v);
}
static __device__ __forceinline__ float bf_hi(unsigned int u) {
    unsigned int v = u & 0xffff0000u;
    return *reinterpret_cast<float*>(&v);
}

static __device__ __forceinline__ float fexp2(float x) {
#if __has_builtin(__builtin_amdgcn_exp2f)
    return __builtin_amdgcn_exp2f(x);
#else
    return exp2f(x);
#endif
}
static __device__ __forceinline__ float frcp(float x) {
#if __has_builtin(__builtin_amdgcn_rcpf)
    return __builtin_amdgcn_rcpf(x);
#else
    return 1.0f / x;
#endif
}

// tanh-form GELU: x * sigmoid(2*c1*(x + 0.044715 x^3)), via exp2 (+rcp).
// Unimodal: single minimum at x ~ -0.75.
static __device__ __forceinline__ float fast_gelu(float x) {
    float x2 = x * x;
    float inner = fmaf(0.044715f * x2, x, x);
    float e = fexp2(inner * 2.3022082f);      // 2*0.7978845608*log2(e)
    float r = frcp(1.0f + e);
    return x * (e * r);
}

// ---------------- K0: zero the stats accumulators (ws is poisoned 0xAA) ----
__global__ void zero_stats(float* stats) {
    for (int i = threadIdx.x; i < 384; i += 256) stats[i] = 0.f;
}

// ---------------- K1: conv 3x3 s2 p1 + bias, 1 output column per thread ----
// 401408 threads = 1568 blocks (6.1/CU, balanced). 27 taps in registers,
// all 192 ocs per thread (tap loads fully amortized). Weights scalar path.
__global__ __launch_bounds__(256) void conv_kernel(
    const float* __restrict__ x, const float* __restrict__ w,
    const float* __restrict__ bias, __hip_bfloat16* __restrict__ y)
{
    int g = blockIdx.x * 256 + threadIdx.x;      // 0..401407
    int ow = g % OW;
    int t  = g / OW;
    int oh = t % OH;
    int b  = t / OH;

    int ih0 = 2 * oh - 1;
    int iw0 = 2 * ow - 1;

    float xv[CIN][3][3];
    #pragma unroll
    for (int c = 0; c < CIN; ++c) {
        #pragma unroll
        for (int r = 0; r < 3; ++r) {
            int ih = ih0 + r;
            bool rv = (ih >= 0) && (ih < H_);
            const float* xrow = x + (((size_t)b * CIN + c) * H_ + (rv ? ih : 0)) * W_;
            #pragma unroll
            for (int j = 0; j < 3; ++j) {
                int iw = iw0 + j;
                bool v = rv && (iw >= 0) && (iw < W_);
                xv[c][r][j] = v ? xrow[iw] : 0.f;
            }
        }
    }

    unsigned short* yp = reinterpret_cast<unsigned short*>(y) +
                         (size_t)b * OC * PLANE + oh * OW + ow;

    #pragma unroll 2
    for (int oc = 0; oc < OC; ++oc) {
        float a = bias[oc];
        const float* wp = w + oc * 27;
        #pragma unroll
        for (int c = 0; c < CIN; ++c)
            #pragma unroll
            for (int r = 0; r < 3; ++r)
                #pragma unroll
                for (int j = 0; j < 3; ++j)
                    a = fmaf(wp[c * 9 + r * 3 + j], xv[c][r][j], a);
        yp[(size_t)oc * PLANE] = f2bf(a);
    }
}

// ---------------- K2: per-channel sum / sumsq over y (BW-saturated) -------
__global__ __launch_bounds__(256) void stats_kernel(
    const __hip_bfloat16* __restrict__ y, float* __restrict__ stats)
{
    int plane = blockIdx.x;            // b*OC + oc, 6144 blocks
    int oc = plane % OC;
    const unsigned int* p =
        reinterpret_cast<const unsigned int*>(y) + plane * (PLANE / 2);

    float s = 0.f, s2 = 0.f;
    for (int ch = threadIdx.x; ch < PLANE / 8; ch += 256) {
        uint4 v = reinterpret_cast<const uint4*>(p)[ch];
        unsigned int u[4] = {v.x, v.y, v.z, v.w};
        #pragma unroll
        for (int k = 0; k < 4; ++k) {
            float lo = bf_lo(u[k]);
            float hi = bf_hi(u[k]);
            s  += lo + hi;
            s2 += lo * lo + hi * hi;
        }
    }

    __shared__ float ls[256], ls2[256];
    int tid = threadIdx.x;
    ls[tid] = s; ls2[tid] = s2;
    __syncthreads();
    for (int off = 128; off > 0; off >>= 1) {
        if (tid < off) { ls[tid] += ls[tid + off]; ls2[tid] += ls2[tid + off]; }
        __syncthreads();
    }
    if (tid == 0) {
        atomicAdd(&stats[oc], ls[0]);
        atomicAdd(&stats[OC + oc], ls2[0]);
    }
}

// ---------------- K3: min/max pool (4 outputs/thread) + BN + 2x GELU ------
// Column min/max over the 3-row window, then per output:
// max(GELU(affine(wmin)), GELU(affine(wmax)))  [GELU unimodal].
__global__ __launch_bounds__(256) void pool_kernel(
    const __hip_bfloat16* __restrict__ y, const float* __restrict__ stats,
    const float* __restrict__ gamma, const float* __restrict__ beta,
    float* __restrict__ out)
{
    int g = blockIdx.x * 256 + threadIdx.x;     // 4,816,896 total
    int j  = g % (PW / 4);                      // col-group 0..13 (4 outputs)
    int t  = g / (PW / 4);
    int ph = t % PH;
    int plane = t / PH;                         // b*OC + oc
    int oc = plane % OC;

    const unsigned int* p32 =
        reinterpret_cast<const unsigned int*>(y) + (size_t)plane * (PLANE / 2);

    // uint index of element 8j-2 within a row; k=0 clamped for j==0
    int bi  = 4 * j - 1;
    int bi0 = (bi < 0) ? 0 : bi;

    float cmax[10], cmin[10];
    #pragma unroll
    for (int c = 0; c < 10; ++c) { cmax[c] = -INFINITY; cmin[c] = INFINITY; }

    #pragma unroll
    for (int rr = 0; rr < 3; ++rr) {
        int ih = 2 * ph - 1 + rr;
        if (ih >= 0) {                           // ih <= 111 always
            const unsigned int* rp = p32 + ih * (OW / 2);
            unsigned int u0 = rp[bi0];
            unsigned int u1 = rp[bi + 1];
            unsigned int u2 = rp[bi + 2];
            unsigned int u3 = rp[bi + 3];
            unsigned int u4 = rp[bi + 4];
            float f0 = bf_lo(u0), f1 = bf_hi(u0);
            float f2 = bf_lo(u1), f3 = bf_hi(u1);
            float f4 = bf_lo(u2), f5 = bf_hi(u2);
            float f6 = bf_lo(u3), f7 = bf_hi(u3);
            float f8 = bf_lo(u4), f9 = bf_hi(u4);
            cmax[0] = fmaxf(cmax[0], f0); cmin[0] = fminf(cmin[0], f0);
            cmax[1] = fmaxf(cmax[1], f1); cmin[1] = fminf(cmin[1], f1);
            cmax[2] = fmaxf(cmax[2], f2); cmin[2] = fminf(cmin[2], f2);
            cmax[3] = fmaxf(cmax[3], f3); cmin[3] = fminf(cmin[3], f3);
            cmax[4] = fmaxf(cmax[4], f4); cmin[4] = fminf(cmin[4], f4);
            cmax[5] = fmaxf(cmax[5], f5); cmin[5] = fminf(cmin[5], f5);
            cmax[6] = fmaxf(cmax[6], f6); cmin[6] = fminf(cmin[6], f6);
            cmax[7] = fmaxf(cmax[7], f7); cmin[7] = fminf(cmin[7], f7);
            cmax[8] = fmaxf(cmax[8], f8); cmin[8] = fminf(cmin[8], f8);
            cmax[9] = fmaxf(cmax[9], f9); cmin[9] = fminf(cmin[9], f9);
        }
    }
    if (j == 0) { cmax[1] = -INFINITY; cmin[1] = INFINITY; }  // col -1 OOB

    float mean = stats[oc] * (1.0f / (float)NSP);
    float var  = fmaf(-mean, mean, stats[OC + oc] * (1.0f / (float)NSP));
    float inv  = rsqrtf(var + 1e-5f);
    float sc   = gamma[oc] * inv;
    float sh   = fmaf(-mean, sc, beta[oc]);

    float4 res;
    float* rp4 = reinterpret_cast<float*>(&res);
    #pragma unroll
    for (int m = 0; m < 4; ++m) {
        float wmax = fmaxf(fmaxf(cmax[2 * m + 1], cmax[2 * m + 2]), cmax[2 * m + 3]);
        float wmin = fminf(fminf(cmin[2 * m + 1], cmin[2 * m + 2]), cmin[2 * m + 3]);
        float lo = fmaf(wmin, sc, sh);
        float hi = fmaf(wmax, sc, sh);
        rp4[m] = fmaxf(fast_gelu(lo), fast_gelu(hi));
    }

    *reinterpret_cast<float4*>(out + (size_t)plane * (PH * PW) + ph * PW + 4 * j) = res;
}

extern "C" void kernel_launch(void* const* d_in, const int* in_sizes, int n_in,
                              void* d_out, int out_size, void* d_ws, size_t ws_size,
                              hipStream_t stream) {
    const float* x     = (const float*)d_in[0];
    const float* w     = (const float*)d_in[1];
    const float* bias  = (const float*)d_in[2];
    const float* gamma = (const float*)d_in[3];
    const float* beta  = (const float*)d_in[4];
    float* out = (float*)d_out;

    float* stats = (float*)d_ws;                                   // 384 floats of sums
    __hip_bfloat16* y = (__hip_bfloat16*)((char*)d_ws + 4096);     // 154.1 MB bf16

    hipLaunchKernelGGL(zero_stats, dim3(1), dim3(256), 0, stream, stats);
    hipLaunchKernelGGL(conv_kernel, dim3(B_ * OH * OW / 256), dim3(256), 0, stream,
                       x, w, bias, y);
    hipLaunchKernelGGL(stats_kernel, dim3(B_ * OC), dim3(256), 0, stream, y, stats);
    hipLaunchKernelGGL(pool_kernel, dim3(B_ * OC * PH * (PW / 4) / 256), dim3(256), 0,
                       stream, y, stats, gamma, beta, out);
}